// Round 8
// baseline (193.944 us; speedup 1.0000x reference)
//
#include <hip/hip_runtime.h>
#include <hip/hip_bf16.h>
#include <stddef.h>

#define NB 8
#define NC 256
#define NL 2048

typedef __attribute__((ext_vector_type(8))) short s16x8;
typedef __attribute__((ext_vector_type(4))) float f32x4;

__device__ __forceinline__ short f2bs(float x){
  __hip_bfloat16 h = __float2bfloat16(x);
  return __builtin_bit_cast(short, h);
}

#define MFMA16(a,b,c) __builtin_amdgcn_mfma_f32_16x16x32_bf16((a),(b),(c),0,0,0)

// ---------------- weight prep: fp32 -> bf16, fold 1/16 scale into Wq ----------------
__global__ void k_prep(const float* __restrict__ wq, const float* __restrict__ wk,
                       const float* __restrict__ wv, const float* __restrict__ wo,
                       short* __restrict__ wout){
  int idx = blockIdx.x * 256 + threadIdx.x;          // 0..262143
  int which = idx >> 16;                             // uniform per block
  int off = idx & 65535;
  const float* src = (which == 0) ? wq : (which == 1) ? wk : (which == 2) ? wv : wo;
  float sc = (which == 0) ? 0.0625f : 1.0f;          // attn scale C^-0.5 folded into Wq
  wout[idx] = f2bs(src[off] * sc);
}

// ---------------- GroupNorm -> ht[b][l][c] (bf16, transposed) ----------------
__global__ void k_gnorm(const float* __restrict__ x, const float* __restrict__ gamma,
                        const float* __restrict__ beta, short* __restrict__ ht){
  const int b = blockIdx.x >> 3, g = blockIdx.x & 7;
  const float* xg = x + ((size_t)(b * NC + g * 32)) * NL;   // 32x2048 contiguous floats
  const int t = threadIdx.x;
  float s = 0.f, ss = 0.f;
  const float4* xg4 = (const float4*)xg;
  for (int i = t; i < 16384; i += 256){
    float4 v = xg4[i];
    s  += v.x + v.y + v.z + v.w;
    ss += v.x*v.x + v.y*v.y + v.z*v.z + v.w*v.w;
  }
  #pragma unroll
  for (int m = 32; m; m >>= 1){ s += __shfl_down(s, m); ss += __shfl_down(ss, m); }
  __shared__ float red[8];
  __shared__ float stat[2];
  if ((t & 63) == 0){ red[t >> 6] = s; red[4 + (t >> 6)] = ss; }
  __syncthreads();
  if (t == 0){
    float S = red[0] + red[1] + red[2] + red[3];
    float SS = red[4] + red[5] + red[6] + red[7];
    float mu = S * (1.f / 65536.f);
    float var = SS * (1.f / 65536.f) - mu * mu;
    stat[0] = mu; stat[1] = rsqrtf(var + 1e-5f);
  }
  __syncthreads();
  const float mu = stat[0], rstd = stat[1];
  const int cc = t >> 3, lch = t & 7;
  const int c = g * 32 + cc;
  const float gsc = gamma[c] * rstd;
  const float gbi = beta[c] - mu * gsc;
  __shared__ short tile[64 * 33];                 // padded to kill bank conflicts
  const int ll_s = t & 63, cg = t >> 6;
  for (int lt = 0; lt < 32; ++lt){
    const int l0 = lt * 64;
    const float4* rp = (const float4*)(xg + (size_t)cc * NL + l0 + lch * 8);
    float4 a = rp[0], bv = rp[1];
    float vals[8] = {a.x, a.y, a.z, a.w, bv.x, bv.y, bv.z, bv.w};
    short o[8];
    #pragma unroll
    for (int e = 0; e < 8; ++e) o[e] = f2bs(vals[e] * gsc + gbi);
    __syncthreads();
    #pragma unroll
    for (int e = 0; e < 8; ++e) tile[(lch * 8 + e) * 33 + cc] = o[e];
    __syncthreads();
    s16x8 pk;
    #pragma unroll
    for (int e = 0; e < 8; ++e) pk[e] = tile[ll_s * 33 + cg * 8 + e];
    *(s16x8*)(ht + ((size_t)(b * NL) + l0 + ll_s) * NC + g * 32 + cg * 8) = pk;
  }
}

// ---------------- q,k conv: D[m=l][n=o] = sum_c ht[l][c] * W[o][c]  -> qt/kt[b][l][o] ----------------
__global__ __launch_bounds__(256) void k_conv_qk(const short* __restrict__ ht, const short* __restrict__ wbf,
                                                 const float* __restrict__ bq, const float* __restrict__ bk,
                                                 short* __restrict__ qt, short* __restrict__ kt){
  const int b = blockIdx.z & 7, which = blockIdx.z >> 3;
  const short* wmat = wbf + (which ? 65536 : 0);
  const float* bias = which ? bk : bq;
  const float bsc = which ? 1.0f : 0.0625f;
  short* outp = which ? kt : qt;
  const int lane = threadIdx.x & 63, wid = threadIdx.x >> 6;
  const int wr = wid >> 1, wc = wid & 1;
  const int l0 = blockIdx.y * 128 + wr * 64;   // m-base
  const int o0 = blockIdx.x * 64 + wc * 32;    // n-base
  const int kgrp = (lane >> 4) * 8;
  const short* aptr = ht + ((size_t)(b * NL) + l0 + (lane & 15)) * NC + kgrp;
  const short* bptr = wmat + (size_t)(o0 + (lane & 15)) * NC + kgrp;
  f32x4 acc[4][2];
  #pragma unroll
  for (int i = 0; i < 4; ++i){
    #pragma unroll
    for (int j = 0; j < 2; ++j){ f32x4 z = {0.f,0.f,0.f,0.f}; acc[i][j] = z; }
  }
  #pragma unroll 2
  for (int kk = 0; kk < 256; kk += 32){
    s16x8 af[4], bfr[2];
    #pragma unroll
    for (int mf = 0; mf < 4; ++mf) af[mf] = *(const s16x8*)(aptr + (size_t)(mf * 16) * NC + kk);
    #pragma unroll
    for (int nf = 0; nf < 2; ++nf) bfr[nf] = *(const s16x8*)(bptr + (size_t)(nf * 16) * NC + kk);
    #pragma unroll
    for (int mf = 0; mf < 4; ++mf)
      #pragma unroll
      for (int nf = 0; nf < 2; ++nf)
        acc[mf][nf] = MFMA16(af[mf], bfr[nf], acc[mf][nf]);
  }
  #pragma unroll
  for (int nf = 0; nf < 2; ++nf){
    const int oc = o0 + nf * 16 + (lane & 15);
    const float bb = bias[oc] * bsc;
    #pragma unroll
    for (int mf = 0; mf < 4; ++mf){
      #pragma unroll
      for (int r = 0; r < 4; ++r){
        const int lr = l0 + mf * 16 + (lane >> 4) * 4 + r;
        outp[((size_t)(b * NL) + lr) * NC + oc] = f2bs(acc[mf][nf][r] + bb);
      }
    }
  }
}

// ---------------- v conv: D[m=o][n=l] = sum_c W[o][c] * ht[l][c]  -> v[b][o][l] ----------------
__global__ __launch_bounds__(256) void k_conv_v(const short* __restrict__ ht, const short* __restrict__ wv,
                                                const float* __restrict__ bv, short* __restrict__ vout){
  const int b = blockIdx.z;
  const int lane = threadIdx.x & 63, wid = threadIdx.x >> 6;
  const int wr = wid >> 1, wc = wid & 1;
  const int o0 = blockIdx.y * 128 + wr * 64;   // m-base
  const int l0 = blockIdx.x * 64 + wc * 32;    // n-base
  const int kgrp = (lane >> 4) * 8;
  const short* aptr = wv + (size_t)(o0 + (lane & 15)) * NC + kgrp;
  const short* bptr = ht + ((size_t)(b * NL) + l0 + (lane & 15)) * NC + kgrp;
  f32x4 acc[4][2];
  #pragma unroll
  for (int i = 0; i < 4; ++i){
    #pragma unroll
    for (int j = 0; j < 2; ++j){ f32x4 z = {0.f,0.f,0.f,0.f}; acc[i][j] = z; }
  }
  #pragma unroll 2
  for (int kk = 0; kk < 256; kk += 32){
    s16x8 af[4], bfr[2];
    #pragma unroll
    for (int mf = 0; mf < 4; ++mf) af[mf] = *(const s16x8*)(aptr + (size_t)(mf * 16) * NC + kk);
    #pragma unroll
    for (int nf = 0; nf < 2; ++nf) bfr[nf] = *(const s16x8*)(bptr + (size_t)(nf * 16) * NC + kk);
    #pragma unroll
    for (int mf = 0; mf < 4; ++mf)
      #pragma unroll
      for (int nf = 0; nf < 2; ++nf)
        acc[mf][nf] = MFMA16(af[mf], bfr[nf], acc[mf][nf]);
  }
  #pragma unroll
  for (int mf = 0; mf < 4; ++mf){
    #pragma unroll
    for (int r = 0; r < 4; ++r){
      const int orow = o0 + mf * 16 + (lane >> 4) * 4 + r;
      const float bb = bv[orow];
      #pragma unroll
      for (int nf = 0; nf < 2; ++nf){
        const int lcol = l0 + nf * 16 + (lane & 15);
        vout[((size_t)(b * NC) + orow) * NL + lcol] = f2bs(acc[mf][nf][r] + bb);
      }
    }
  }
}

// ---------------- flash attention, double-buffered LDS K/V pipeline ----------------
// Block = 64 q-rows (4 waves x 16), all waves sweep the full j-range together.
// K tiles [2][64][256] and V tiles [2][256][64] staged via global_load_lds (w=16),
// pre-swizzled global source (linear LDS dest) + XOR-swizzled ds_reads:
//   K: byte ^= (row&15)<<4   V: byte ^= (row&7)<<4
// One barrier + one vmcnt(0) per tile (T3 minimum-2-phase): STAGE(t+1 -> buf^1)
// issued FIRST, whole tile compute on buf hides the staging latency, then
// vmcnt(0)+s_barrier flips buffers. (Round-7 evidence: 3-barrier schedule at
// 1 wave/SIMD left 7400 cy/tile vs ~2000 cy of issue.)
// XCD remap: b = flat&7 keeps batch b's K/V in XCD b's L2 (round-6 verified).
__global__ __launch_bounds__(256, 2) void k_flash(const short* __restrict__ qt, const short* __restrict__ kt,
                                                  const short* __restrict__ v, short* __restrict__ ao){
  const int flat = blockIdx.x;
  const int b = flat & 7;
  const int i0 = (flat >> 3) * 64;
  const int lane = threadIdx.x & 63, wid = threadIdx.x >> 6;
  __shared__ short k_lds[2][64 * 256];            // 64 KB
  __shared__ short v_lds[2][256 * 64];            // 64 KB
  __shared__ short plds[4][1024];                 // 8 KB, per-wave 16x64 P tile
  short* pl = plds[wid];
  const int arow = lane & 15, kg = lane >> 4;

  const short* qp = qt + ((size_t)(b * NL) + i0 + wid * 16 + arow) * NC + kg * 8;
  s16x8 qf[8];
  #pragma unroll
  for (int kc = 0; kc < 8; ++kc) qf[kc] = *(const s16x8*)(qp + kc * 32);

  f32x4 oacc[16];
  #pragma unroll
  for (int i = 0; i < 16; ++i){ f32x4 z = {0.f,0.f,0.f,0.f}; oacc[i] = z; }
  float m_r[4], l_r[4];
  #pragma unroll
  for (int r = 0; r < 4; ++r){ m_r[r] = -3.0e38f; l_r[r] = 0.f; }

  // --- staging: 8 global_load_lds (16B) per thread per tile per matrix, linear dest ---
  auto STAGE_K = [&](int jt, int buf){
    const int j0 = jt * 64;
    #pragma unroll
    for (int t = 0; t < 8; ++t){
      const int i = wid * 8 + t;                  // wave-instr index, 2 rows each
      const int r = 2 * i + (lane >> 5);
      const int wb = (lane & 31) * 16;            // byte offset within 512B row
      const short* src = kt + ((size_t)(b * NL) + j0 + r) * NC + ((wb ^ ((r & 15) << 4)) >> 1);
      __builtin_amdgcn_global_load_lds((const __attribute__((address_space(1))) void*)src,
                                       (__attribute__((address_space(3))) void*)&k_lds[buf][i * 512], 16, 0, 0);
    }
  };
  auto STAGE_V = [&](int jt, int buf){
    const int j0 = jt * 64;
    #pragma unroll
    for (int t = 0; t < 8; ++t){
      const int i = wid * 8 + t;                  // 8 V-rows (128B) each
      const int rc = 8 * i + (lane >> 3);
      const int wb = (lane & 7) * 16;             // byte offset within 128B row
      const short* src = v + ((size_t)(b * NC) + rc) * NL + j0 + ((wb ^ ((rc & 7) << 4)) >> 1);
      __builtin_amdgcn_global_load_lds((const __attribute__((address_space(1))) void*)src,
                                       (__attribute__((address_space(3))) void*)&v_lds[buf][i * 512], 16, 0, 0);
    }
  };

  STAGE_K(0, 0);
  STAGE_V(0, 0);
  asm volatile("s_waitcnt vmcnt(0)" ::: "memory");
  __builtin_amdgcn_s_barrier();
  __builtin_amdgcn_sched_barrier(0);

  int cur = 0;
  for (int jt = 0; jt < 32; ++jt){
    // ---- prefetch next tile into the other buffer (lands under this tile's compute) ----
    if (jt + 1 < 32){
      STAGE_K(jt + 1, cur ^ 1);
      STAGE_V(jt + 1, cur ^ 1);
    }
    const short* kl = k_lds[cur];
    const short* vl = v_lds[cur];
    // ---- QK^T from k_lds[cur] ----
    f32x4 sf[4];
    #pragma unroll
    for (int nf = 0; nf < 4; ++nf){ f32x4 z = {0.f,0.f,0.f,0.f}; sf[nf] = z; }
    #pragma unroll
    for (int kc = 0; kc < 8; ++kc){
      #pragma unroll
      for (int nf = 0; nf < 4; ++nf){
        const int r = nf * 16 + arow;
        s16x8 kf = *(const s16x8*)&kl[r * 256 + (((kc * 64 + kg * 16) ^ ((arow & 15) << 4)) >> 1)];
        sf[nf] = MFMA16(qf[kc], kf, sf[nf]);
      }
    }
    // ---- online softmax ----
    float corr[4];
    #pragma unroll
    for (int r = 0; r < 4; ++r){
      float mx = fmaxf(fmaxf(sf[0][r], sf[1][r]), fmaxf(sf[2][r], sf[3][r]));
      #pragma unroll
      for (int d = 1; d < 16; d <<= 1) mx = fmaxf(mx, __shfl_xor(mx, d));
      const float mn = fmaxf(m_r[r], mx);
      corr[r] = __expf(m_r[r] - mn);
      float rs = 0.f;
      #pragma unroll
      for (int nf = 0; nf < 4; ++nf){
        float p = __expf(sf[nf][r] - mn);
        sf[nf][r] = p;
        rs += p;
      }
      #pragma unroll
      for (int d = 1; d < 16; d <<= 1) rs += __shfl_xor(rs, d);
      l_r[r] = l_r[r] * corr[r] + rs;
      m_r[r] = mn;
    }
    #pragma unroll
    for (int i = 0; i < 16; ++i){
      f32x4 t = oacc[i];
      t[0] *= corr[0]; t[1] *= corr[1]; t[2] *= corr[2]; t[3] *= corr[3];
      oacc[i] = t;
    }
    // ---- P -> per-wave LDS (XOR swizzle; wave-private, no cross-wave sync) ----
    #pragma unroll
    for (int r = 0; r < 4; ++r){
      const int rowp = kg * 4 + r;
      const int swz = (rowp & 7) << 3;
      #pragma unroll
      for (int nf = 0; nf < 4; ++nf){
        const int col = nf * 16 + arow;
        pl[rowp * 64 + (col ^ swz)] = f2bs(sf[nf][r]);
      }
    }
    // ---- PV from v_lds[cur] ----
    #pragma unroll
    for (int kc2 = 0; kc2 < 2; ++kc2){
      const int swz2 = (arow & 7) << 3;
      s16x8 pa = *(const s16x8*)(pl + arow * 64 + ((kc2 * 32 + kg * 8) ^ swz2));
      #pragma unroll
      for (int nf2 = 0; nf2 < 16; ++nf2){
        const int rc = nf2 * 16 + arow;
        s16x8 vf = *(const s16x8*)&vl[rc * 64 + (((kc2 * 64 + kg * 16) ^ ((arow & 7) << 4)) >> 1)];
        oacc[nf2] = MFMA16(pa, vf, oacc[nf2]);
      }
    }
    // ---- flip: next tile fully staged + everyone done reading cur ----
    asm volatile("s_waitcnt vmcnt(0)" ::: "memory");
    __builtin_amdgcn_s_barrier();
    __builtin_amdgcn_sched_barrier(0);
    cur ^= 1;
  }

  // ---- epilogue: direct store (each wave owns complete rows) ----
  #pragma unroll
  for (int r = 0; r < 4; ++r){
    const float inv = 1.f / l_r[r];
    const int irow = i0 + wid * 16 + kg * 4 + r;
    #pragma unroll
    for (int nf2 = 0; nf2 < 16; ++nf2){
      ao[((size_t)(b * NL) + irow) * NC + nf2 * 16 + arow] = f2bs(oacc[nf2][r] * inv);
    }
  }
}

// ---------------- final conv + bias + residual: out = x + Wo@ao + bo (fp32) ----------------
__global__ __launch_bounds__(256) void k_final(const short* __restrict__ ao, const short* __restrict__ wo,
                                               const float* __restrict__ bo, const float* __restrict__ x,
                                               float* __restrict__ out){
  const int b = blockIdx.z;
  const int lane = threadIdx.x & 63, wid = threadIdx.x >> 6;
  const int wr = wid >> 1, wc = wid & 1;
  const int o0 = blockIdx.y * 128 + wr * 64;   // m-base
  const int i0 = blockIdx.x * 64 + wc * 32;    // n-base
  const int kgrp = (lane >> 4) * 8;
  const short* aptr = wo + (size_t)(o0 + (lane & 15)) * NC + kgrp;
  const short* bptr = ao + ((size_t)(b * NL) + i0 + (lane & 15)) * NC + kgrp;
  f32x4 acc[4][2];
  #pragma unroll
  for (int i = 0; i < 4; ++i){
    #pragma unroll
    for (int j = 0; j < 2; ++j){ f32x4 z = {0.f,0.f,0.f,0.f}; acc[i][j] = z; }
  }
  #pragma unroll 2
  for (int kk = 0; kk < 256; kk += 32){
    s16x8 af[4], bfr[2];
    #pragma unroll
    for (int mf = 0; mf < 4; ++mf) af[mf] = *(const s16x8*)(aptr + (size_t)(mf * 16) * NC + kk);
    #pragma unroll
    for (int nf = 0; nf < 2; ++nf) bfr[nf] = *(const s16x8*)(bptr + (size_t)(nf * 16) * NC + kk);
    #pragma unroll
    for (int mf = 0; mf < 4; ++mf)
      #pragma unroll
      for (int nf = 0; nf < 2; ++nf)
        acc[mf][nf] = MFMA16(af[mf], bfr[nf], acc[mf][nf]);
  }
  #pragma unroll
  for (int mf = 0; mf < 4; ++mf){
    #pragma unroll
    for (int r = 0; r < 4; ++r){
      const int orow = o0 + mf * 16 + (lane >> 4) * 4 + r;
      const float bb = bo[orow];
      #pragma unroll
      for (int nf = 0; nf < 2; ++nf){
        const int icol = i0 + nf * 16 + (lane & 15);
        const size_t idx = ((size_t)(b * NC) + orow) * NL + icol;
        out[idx] = acc[mf][nf][r] + bb + x[idx];
      }
    }
  }
}

extern "C" void kernel_launch(void* const* d_in, const int* in_sizes, int n_in,
                              void* d_out, int out_size, void* d_ws, size_t ws_size,
                              hipStream_t stream){
  const float* x     = (const float*)d_in[0];
  const float* gamma = (const float*)d_in[1];
  const float* beta  = (const float*)d_in[2];
  const float* Wq    = (const float*)d_in[3];
  const float* bq    = (const float*)d_in[4];
  const float* Wk    = (const float*)d_in[5];
  const float* bk    = (const float*)d_in[6];
  const float* Wv    = (const float*)d_in[7];
  const float* bv    = (const float*)d_in[8];
  const float* Wo    = (const float*)d_in[9];
  const float* bo    = (const float*)d_in[10];
  float* out = (float*)d_out;

  char* ws = (char*)d_ws;
  // layout (bytes): wbf 512K | ht 8M | qt 8M | kt 8M | v 8M   (ao aliases qt: each
  // flash block reads only its own qt rows before writing the same ao rows)
  short* wbf = (short*)ws;
  short* ht  = (short*)(ws + (size_t)524288);
  short* qt  = (short*)(ws + (size_t)524288 + 8388608);
  short* ktp = (short*)(ws + (size_t)524288 + 2 * 8388608);
  short* vp  = (short*)(ws + (size_t)524288 + 3 * 8388608);
  short* aop = qt;

  k_prep <<<1024, 256, 0, stream>>>(Wq, Wk, Wv, Wo, wbf);
  k_gnorm<<<64, 256, 0, stream>>>(x, gamma, beta, ht);
  k_conv_qk<<<dim3(4, 16, 16), 256, 0, stream>>>(ht, wbf, bq, bk, qt, ktp);
  k_conv_v <<<dim3(32, 2, 8), 256, 0, stream>>>(ht, wbf + 2 * 65536, bv, vp);
  k_flash  <<<dim3(256), 256, 0, stream>>>(qt, ktp, vp, aop);
  k_final  <<<dim3(32, 2, 8), 256, 0, stream>>>(aop, wbf + 3 * 65536, bo, x, out);
}

// Round 9
// 164.815 us; speedup vs baseline: 1.1767x; 1.1767x over previous
//
#include <hip/hip_runtime.h>
#include <hip/hip_bf16.h>
#include <stddef.h>

#define NB 8
#define NC 256
#define NL 2048

typedef __attribute__((ext_vector_type(8))) short s16x8;
typedef __attribute__((ext_vector_type(4))) float f32x4;

__device__ __forceinline__ short f2bs(float x){
  __hip_bfloat16 h = __float2bfloat16(x);
  return __builtin_bit_cast(short, h);
}
__device__ __forceinline__ float bs2f(short x){
  unsigned u = ((unsigned)(unsigned short)x) << 16;
  return __builtin_bit_cast(float, u);
}

#define MFMA16(a,b,c) __builtin_amdgcn_mfma_f32_16x16x32_bf16((a),(b),(c),0,0,0)

// ---------------- weight prep: fp32 -> bf16, fold 1/16 scale into Wq ----------------
__global__ void k_prep(const float* __restrict__ wq, const float* __restrict__ wk,
                       const float* __restrict__ wv, const float* __restrict__ wo,
                       short* __restrict__ wout){
  int idx = blockIdx.x * 256 + threadIdx.x;          // 0..262143
  int which = idx >> 16;                             // uniform per block
  int off = idx & 65535;
  const float* src = (which == 0) ? wq : (which == 1) ? wk : (which == 2) ? wv : wo;
  float sc = (which == 0) ? 0.0625f : 1.0f;          // attn scale C^-0.5 folded into Wq
  wout[idx] = f2bs(src[off] * sc);
}

// ---------------- GroupNorm -> ht[b][l][c] (bf16, transposed) ----------------
__global__ void k_gnorm(const float* __restrict__ x, const float* __restrict__ gamma,
                        const float* __restrict__ beta, short* __restrict__ ht){
  const int b = blockIdx.x >> 3, g = blockIdx.x & 7;
  const float* xg = x + ((size_t)(b * NC + g * 32)) * NL;   // 32x2048 contiguous floats
  const int t = threadIdx.x;
  float s = 0.f, ss = 0.f;
  const float4* xg4 = (const float4*)xg;
  for (int i = t; i < 16384; i += 256){
    float4 v = xg4[i];
    s  += v.x + v.y + v.z + v.w;
    ss += v.x*v.x + v.y*v.y + v.z*v.z + v.w*v.w;
  }
  #pragma unroll
  for (int m = 32; m; m >>= 1){ s += __shfl_down(s, m); ss += __shfl_down(ss, m); }
  __shared__ float red[8];
  __shared__ float stat[2];
  if ((t & 63) == 0){ red[t >> 6] = s; red[4 + (t >> 6)] = ss; }
  __syncthreads();
  if (t == 0){
    float S = red[0] + red[1] + red[2] + red[3];
    float SS = red[4] + red[5] + red[6] + red[7];
    float mu = S * (1.f / 65536.f);
    float var = SS * (1.f / 65536.f) - mu * mu;
    stat[0] = mu; stat[1] = rsqrtf(var + 1e-5f);
  }
  __syncthreads();
  const float mu = stat[0], rstd = stat[1];
  const int cc = t >> 3, lch = t & 7;
  const int c = g * 32 + cc;
  const float gsc = gamma[c] * rstd;
  const float gbi = beta[c] - mu * gsc;
  __shared__ short tile[64 * 33];                 // padded to kill bank conflicts
  const int ll_s = t & 63, cg = t >> 6;
  for (int lt = 0; lt < 32; ++lt){
    const int l0 = lt * 64;
    const float4* rp = (const float4*)(xg + (size_t)cc * NL + l0 + lch * 8);
    float4 a = rp[0], bv = rp[1];
    float vals[8] = {a.x, a.y, a.z, a.w, bv.x, bv.y, bv.z, bv.w};
    short o[8];
    #pragma unroll
    for (int e = 0; e < 8; ++e) o[e] = f2bs(vals[e] * gsc + gbi);
    __syncthreads();
    #pragma unroll
    for (int e = 0; e < 8; ++e) tile[(lch * 8 + e) * 33 + cc] = o[e];
    __syncthreads();
    s16x8 pk;
    #pragma unroll
    for (int e = 0; e < 8; ++e) pk[e] = tile[ll_s * 33 + cg * 8 + e];
    *(s16x8*)(ht + ((size_t)(b * NL) + l0 + ll_s) * NC + g * 32 + cg * 8) = pk;
  }
}

// ---------------- q,k conv: D[m=l][n=o] = sum_c ht[l][c] * W[o][c]  -> qt/kt[b][l][o] ----------------
__global__ __launch_bounds__(256) void k_conv_qk(const short* __restrict__ ht, const short* __restrict__ wbf,
                                                 const float* __restrict__ bq, const float* __restrict__ bk,
                                                 short* __restrict__ qt, short* __restrict__ kt){
  const int b = blockIdx.z & 7, which = blockIdx.z >> 3;
  const short* wmat = wbf + (which ? 65536 : 0);
  const float* bias = which ? bk : bq;
  const float bsc = which ? 1.0f : 0.0625f;
  short* outp = which ? kt : qt;
  const int lane = threadIdx.x & 63, wid = threadIdx.x >> 6;
  const int wr = wid >> 1, wc = wid & 1;
  const int l0 = blockIdx.y * 128 + wr * 64;   // m-base
  const int o0 = blockIdx.x * 64 + wc * 32;    // n-base
  const int kgrp = (lane >> 4) * 8;
  const short* aptr = ht + ((size_t)(b * NL) + l0 + (lane & 15)) * NC + kgrp;
  const short* bptr = wmat + (size_t)(o0 + (lane & 15)) * NC + kgrp;
  f32x4 acc[4][2];
  #pragma unroll
  for (int i = 0; i < 4; ++i){
    #pragma unroll
    for (int j = 0; j < 2; ++j){ f32x4 z = {0.f,0.f,0.f,0.f}; acc[i][j] = z; }
  }
  #pragma unroll 2
  for (int kk = 0; kk < 256; kk += 32){
    s16x8 af[4], bfr[2];
    #pragma unroll
    for (int mf = 0; mf < 4; ++mf) af[mf] = *(const s16x8*)(aptr + (size_t)(mf * 16) * NC + kk);
    #pragma unroll
    for (int nf = 0; nf < 2; ++nf) bfr[nf] = *(const s16x8*)(bptr + (size_t)(nf * 16) * NC + kk);
    #pragma unroll
    for (int mf = 0; mf < 4; ++mf)
      #pragma unroll
      for (int nf = 0; nf < 2; ++nf)
        acc[mf][nf] = MFMA16(af[mf], bfr[nf], acc[mf][nf]);
  }
  #pragma unroll
  for (int nf = 0; nf < 2; ++nf){
    const int oc = o0 + nf * 16 + (lane & 15);
    const float bb = bias[oc] * bsc;
    #pragma unroll
    for (int mf = 0; mf < 4; ++mf){
      #pragma unroll
      for (int r = 0; r < 4; ++r){
        const int lr = l0 + mf * 16 + (lane >> 4) * 4 + r;
        outp[((size_t)(b * NL) + lr) * NC + oc] = f2bs(acc[mf][nf][r] + bb);
      }
    }
  }
}

// ---------------- v conv: D[m=o][n=l] = sum_c W[o][c] * ht[l][c]  -> v[b][o][l] ----------------
__global__ __launch_bounds__(256) void k_conv_v(const short* __restrict__ ht, const short* __restrict__ wv,
                                                const float* __restrict__ bv, short* __restrict__ vout){
  const int b = blockIdx.z;
  const int lane = threadIdx.x & 63, wid = threadIdx.x >> 6;
  const int wr = wid >> 1, wc = wid & 1;
  const int o0 = blockIdx.y * 128 + wr * 64;   // m-base
  const int l0 = blockIdx.x * 64 + wc * 32;    // n-base
  const int kgrp = (lane >> 4) * 8;
  const short* aptr = wv + (size_t)(o0 + (lane & 15)) * NC + kgrp;
  const short* bptr = ht + ((size_t)(b * NL) + l0 + (lane & 15)) * NC + kgrp;
  f32x4 acc[4][2];
  #pragma unroll
  for (int i = 0; i < 4; ++i){
    #pragma unroll
    for (int j = 0; j < 2; ++j){ f32x4 z = {0.f,0.f,0.f,0.f}; acc[i][j] = z; }
  }
  #pragma unroll 2
  for (int kk = 0; kk < 256; kk += 32){
    s16x8 af[4], bfr[2];
    #pragma unroll
    for (int mf = 0; mf < 4; ++mf) af[mf] = *(const s16x8*)(aptr + (size_t)(mf * 16) * NC + kk);
    #pragma unroll
    for (int nf = 0; nf < 2; ++nf) bfr[nf] = *(const s16x8*)(bptr + (size_t)(nf * 16) * NC + kk);
    #pragma unroll
    for (int mf = 0; mf < 4; ++mf)
      #pragma unroll
      for (int nf = 0; nf < 2; ++nf)
        acc[mf][nf] = MFMA16(af[mf], bfr[nf], acc[mf][nf]);
  }
  #pragma unroll
  for (int mf = 0; mf < 4; ++mf){
    #pragma unroll
    for (int r = 0; r < 4; ++r){
      const int orow = o0 + mf * 16 + (lane >> 4) * 4 + r;
      const float bb = bv[orow];
      #pragma unroll
      for (int nf = 0; nf < 2; ++nf){
        const int lcol = l0 + nf * 16 + (lane & 15);
        vout[((size_t)(b * NC) + orow) * NL + lcol] = f2bs(acc[mf][nf][r] + bb);
      }
    }
  }
}

// ---------------- flash attention, LDS-staged, block-level split-KV x2 ----------------
// Grid 512: flat -> b = flat&7 (XCD-local K/V, round-6 verified), rest = flat>>3,
// h = rest&1 (KV half: j in [h*1024, h*1024+1024)), i0 = (rest>>1)*64.
// 2 blocks/CU (LDS 72 KB x2 <= 160 KB) -> 2 waves/SIMD with INDEPENDENT barriers:
// one block's waves compute while the other's stall (round-8 lesson: 1 wave/SIMD
// leaves the serial QK->softmax->PV chain fully exposed; intra-block split would
// lockstep at shared barriers).
// Writes unnormalized O (bf16) + (m,l) per row; k_merge combines the two halves.
// Schedule per tile (round-7 verified, best measured):
//   QK(t); softmax; vmcnt(0); bar; STAGE_K(t+1); P,PV(t); bar; STAGE_V(t+1);
//   vmcnt(8); bar
__global__ __launch_bounds__(256, 2) void k_flash(const short* __restrict__ qt, const short* __restrict__ kt,
                                                  const short* __restrict__ v, short* __restrict__ po,
                                                  float* __restrict__ ml){
  const int flat = blockIdx.x;
  const int b = flat & 7;
  const int rest = flat >> 3;
  const int h = rest & 1;
  const int i0 = (rest >> 1) * 64;
  const int lane = threadIdx.x & 63, wid = threadIdx.x >> 6;
  __shared__ short k_lds[64 * 256];               // 32 KB
  __shared__ short v_lds[256 * 64];               // 32 KB
  __shared__ short plds[4][1024];                 // 8 KB, per-wave 16x64 P tile
  short* pl = plds[wid];
  const int arow = lane & 15, kg = lane >> 4;

  const short* qp = qt + ((size_t)(b * NL) + i0 + wid * 16 + arow) * NC + kg * 8;
  s16x8 qf[8];
  #pragma unroll
  for (int kc = 0; kc < 8; ++kc) qf[kc] = *(const s16x8*)(qp + kc * 32);

  f32x4 oacc[16];
  #pragma unroll
  for (int i = 0; i < 16; ++i){ f32x4 z = {0.f,0.f,0.f,0.f}; oacc[i] = z; }
  float m_r[4], l_r[4];
  #pragma unroll
  for (int r = 0; r < 4; ++r){ m_r[r] = -3.0e38f; l_r[r] = 0.f; }

  // --- staging: 8 global_load_lds (16B) per thread per tile, linear dest ---
  auto STAGE_K = [&](int jt){
    const int j0 = jt * 64;
    #pragma unroll
    for (int t = 0; t < 8; ++t){
      const int i = wid * 8 + t;                  // wave-instr index, 2 rows each
      const int r = 2 * i + (lane >> 5);
      const int wb = (lane & 31) * 16;            // byte offset within 512B row
      const short* src = kt + ((size_t)(b * NL) + j0 + r) * NC + ((wb ^ ((r & 15) << 4)) >> 1);
      __builtin_amdgcn_global_load_lds((const __attribute__((address_space(1))) void*)src,
                                       (__attribute__((address_space(3))) void*)&k_lds[i * 512], 16, 0, 0);
    }
  };
  auto STAGE_V = [&](int jt){
    const int j0 = jt * 64;
    #pragma unroll
    for (int t = 0; t < 8; ++t){
      const int i = wid * 8 + t;                  // 8 V-rows (128B) each
      const int rc = 8 * i + (lane >> 3);
      const int wb = (lane & 7) * 16;             // byte offset within 128B row
      const short* src = v + ((size_t)(b * NC) + rc) * NL + j0 + ((wb ^ ((rc & 7) << 4)) >> 1);
      __builtin_amdgcn_global_load_lds((const __attribute__((address_space(1))) void*)src,
                                       (__attribute__((address_space(3))) void*)&v_lds[i * 512], 16, 0, 0);
    }
  };

  const int jb0 = h * 16, jend = jb0 + 16;
  STAGE_K(jb0);
  STAGE_V(jb0);
  asm volatile("s_waitcnt vmcnt(0)" ::: "memory");
  __builtin_amdgcn_s_barrier();
  __builtin_amdgcn_sched_barrier(0);

  for (int jt = jb0; jt < jend; ++jt){
    // ---- QK^T from k_lds ----
    f32x4 sf[4];
    #pragma unroll
    for (int nf = 0; nf < 4; ++nf){ f32x4 z = {0.f,0.f,0.f,0.f}; sf[nf] = z; }
    #pragma unroll
    for (int kc = 0; kc < 8; ++kc){
      #pragma unroll
      for (int nf = 0; nf < 4; ++nf){
        const int r = nf * 16 + arow;
        s16x8 kf = *(const s16x8*)&k_lds[r * 256 + (((kc * 64 + kg * 16) ^ ((arow & 15) << 4)) >> 1)];
        sf[nf] = MFMA16(qf[kc], kf, sf[nf]);
      }
    }
    // ---- online softmax ----
    float corr[4];
    #pragma unroll
    for (int r = 0; r < 4; ++r){
      float mx = fmaxf(fmaxf(sf[0][r], sf[1][r]), fmaxf(sf[2][r], sf[3][r]));
      #pragma unroll
      for (int d = 1; d < 16; d <<= 1) mx = fmaxf(mx, __shfl_xor(mx, d));
      const float mn = fmaxf(m_r[r], mx);
      corr[r] = __expf(m_r[r] - mn);
      float rs = 0.f;
      #pragma unroll
      for (int nf = 0; nf < 4; ++nf){
        float p = __expf(sf[nf][r] - mn);
        sf[nf][r] = p;
        rs += p;
      }
      #pragma unroll
      for (int d = 1; d < 16; d <<= 1) rs += __shfl_xor(rs, d);
      l_r[r] = l_r[r] * corr[r] + rs;
      m_r[r] = mn;
    }
    #pragma unroll
    for (int i = 0; i < 16; ++i){
      f32x4 t = oacc[i];
      t[0] *= corr[0]; t[1] *= corr[1]; t[2] *= corr[2]; t[3] *= corr[3];
      oacc[i] = t;
    }
    asm volatile("s_waitcnt vmcnt(0)" ::: "memory");
    __builtin_amdgcn_s_barrier();                 // K(t) reads done + V(t) visible
    __builtin_amdgcn_sched_barrier(0);
    if (jt + 1 < jend) STAGE_K(jt + 1);           // hides under P+PV

    // ---- P -> per-wave LDS (XOR swizzle) ----
    #pragma unroll
    for (int r = 0; r < 4; ++r){
      const int rowp = kg * 4 + r;
      const int swz = (rowp & 7) << 3;
      #pragma unroll
      for (int nf = 0; nf < 4; ++nf){
        const int col = nf * 16 + arow;
        pl[rowp * 64 + (col ^ swz)] = f2bs(sf[nf][r]);
      }
    }
    // ---- PV from v_lds ----
    #pragma unroll
    for (int kc2 = 0; kc2 < 2; ++kc2){
      const int swz2 = (arow & 7) << 3;
      s16x8 pa = *(const s16x8*)(pl + arow * 64 + ((kc2 * 32 + kg * 8) ^ swz2));
      #pragma unroll
      for (int nf2 = 0; nf2 < 16; ++nf2){
        const int rc = nf2 * 16 + arow;
        s16x8 vf = *(const s16x8*)&v_lds[rc * 64 + (((kc2 * 64 + kg * 16) ^ ((arow & 7) << 4)) >> 1)];
        oacc[nf2] = MFMA16(pa, vf, oacc[nf2]);
      }
    }
    __builtin_amdgcn_s_barrier();                 // V(t) reads done
    __builtin_amdgcn_sched_barrier(0);
    if (jt + 1 < jend) STAGE_V(jt + 1);           // hides under next QK+softmax
    asm volatile("s_waitcnt vmcnt(8)" ::: "memory");  // my K(t+1) landed (V(t+1) in flight)
    __builtin_amdgcn_s_barrier();                 // K(t+1) visible to all
    __builtin_amdgcn_sched_barrier(0);
  }

  // ---- epilogue: write unnormalized partial O (bf16) + m,l per row ----
  short* pob = po + (size_t)h * 4194304 + ((size_t)(b * NL) + i0 + wid * 16) * NC;
  #pragma unroll
  for (int r = 0; r < 4; ++r){
    const int irow = kg * 4 + r;
    #pragma unroll
    for (int nf2 = 0; nf2 < 16; ++nf2){
      pob[(size_t)irow * NC + nf2 * 16 + arow] = f2bs(oacc[nf2][r]);
    }
    if (arow == 0){
      const size_t Rg = (size_t)h * 16384 + (size_t)(b * NL) + i0 + wid * 16 + irow;
      ml[Rg * 2 + 0] = m_r[r];
      ml[Rg * 2 + 1] = l_r[r];
    }
  }
}

// ---------------- merge the two KV-halves: ao = (O0*w0 + O1*w1) / (l0*w0 + l1*w1) ----------------
__global__ __launch_bounds__(256) void k_merge(const short* __restrict__ po, const float* __restrict__ ml,
                                               short* __restrict__ ao){
  const int t = threadIdx.x;
  const int R = blockIdx.x * 8 + (t >> 5);        // global row in [0, 16384)
  const int c0 = (t & 31) * 8;
  const float m0 = ml[(size_t)R * 2 + 0], l0 = ml[(size_t)R * 2 + 1];
  const float m1 = ml[((size_t)16384 + R) * 2 + 0], l1 = ml[((size_t)16384 + R) * 2 + 1];
  const float M = fmaxf(m0, m1);
  const float w0 = __expf(m0 - M), w1 = __expf(m1 - M);
  const float inv = 1.f / (l0 * w0 + l1 * w1);
  s16x8 a = *(const s16x8*)(po + (size_t)R * 256 + c0);
  s16x8 c = *(const s16x8*)(po + (size_t)4194304 + (size_t)R * 256 + c0);
  s16x8 o;
  #pragma unroll
  for (int e = 0; e < 8; ++e) o[e] = f2bs((bs2f(a[e]) * w0 + bs2f(c[e]) * w1) * inv);
  *(s16x8*)(ao + (size_t)R * 256 + c0) = o;
}

// ---------------- final conv + bias + residual: out = x + Wo@ao + bo (fp32) ----------------
__global__ __launch_bounds__(256) void k_final(const short* __restrict__ ao, const short* __restrict__ wo,
                                               const float* __restrict__ bo, const float* __restrict__ x,
                                               float* __restrict__ out){
  const int b = blockIdx.z;
  const int lane = threadIdx.x & 63, wid = threadIdx.x >> 6;
  const int wr = wid >> 1, wc = wid & 1;
  const int o0 = blockIdx.y * 128 + wr * 64;   // m-base
  const int i0 = blockIdx.x * 64 + wc * 32;    // n-base
  const int kgrp = (lane >> 4) * 8;
  const short* aptr = wo + (size_t)(o0 + (lane & 15)) * NC + kgrp;
  const short* bptr = ao + ((size_t)(b * NL) + i0 + (lane & 15)) * NC + kgrp;
  f32x4 acc[4][2];
  #pragma unroll
  for (int i = 0; i < 4; ++i){
    #pragma unroll
    for (int j = 0; j < 2; ++j){ f32x4 z = {0.f,0.f,0.f,0.f}; acc[i][j] = z; }
  }
  #pragma unroll 2
  for (int kk = 0; kk < 256; kk += 32){
    s16x8 af[4], bfr[2];
    #pragma unroll
    for (int mf = 0; mf < 4; ++mf) af[mf] = *(const s16x8*)(aptr + (size_t)(mf * 16) * NC + kk);
    #pragma unroll
    for (int nf = 0; nf < 2; ++nf) bfr[nf] = *(const s16x8*)(bptr + (size_t)(nf * 16) * NC + kk);
    #pragma unroll
    for (int mf = 0; mf < 4; ++mf)
      #pragma unroll
      for (int nf = 0; nf < 2; ++nf)
        acc[mf][nf] = MFMA16(af[mf], bfr[nf], acc[mf][nf]);
  }
  #pragma unroll
  for (int mf = 0; mf < 4; ++mf){
    #pragma unroll
    for (int r = 0; r < 4; ++r){
      const int orow = o0 + mf * 16 + (lane >> 4) * 4 + r;
      const float bb = bo[orow];
      #pragma unroll
      for (int nf = 0; nf < 2; ++nf){
        const int icol = i0 + nf * 16 + (lane & 15);
        const size_t idx = ((size_t)(b * NC) + orow) * NL + icol;
        out[idx] = acc[mf][nf][r] + bb + x[idx];
      }
    }
  }
}

extern "C" void kernel_launch(void* const* d_in, const int* in_sizes, int n_in,
                              void* d_out, int out_size, void* d_ws, size_t ws_size,
                              hipStream_t stream){
  const float* x     = (const float*)d_in[0];
  const float* gamma = (const float*)d_in[1];
  const float* beta  = (const float*)d_in[2];
  const float* Wq    = (const float*)d_in[3];
  const float* bq    = (const float*)d_in[4];
  const float* Wk    = (const float*)d_in[5];
  const float* bk    = (const float*)d_in[6];
  const float* Wv    = (const float*)d_in[7];
  const float* bv    = (const float*)d_in[8];
  const float* Wo    = (const float*)d_in[9];
  const float* bo    = (const float*)d_in[10];
  float* out = (float*)d_out;

  char* ws = (char*)d_ws;
  // layout (bytes): wbf 512K | ht 8M | qt 8M | kt 8M | v 8M | po 16M | ml 256K
  // (ao aliases qt: k_merge writes it only after all k_flash blocks finished
  //  reading qt -- separate kernels, stream-ordered)
  short* wbf = (short*)ws;
  short* ht  = (short*)(ws + (size_t)524288);
  short* qt  = (short*)(ws + (size_t)524288 + 8388608);
  short* ktp = (short*)(ws + (size_t)524288 + 2 * 8388608);
  short* vp  = (short*)(ws + (size_t)524288 + 3 * 8388608);
  short* pop = (short*)(ws + (size_t)524288 + 4 * 8388608);
  float* mlp = (float*)(ws + (size_t)524288 + 6 * 8388608);
  short* aop = qt;

  k_prep <<<1024, 256, 0, stream>>>(Wq, Wk, Wv, Wo, wbf);
  k_gnorm<<<64, 256, 0, stream>>>(x, gamma, beta, ht);
  k_conv_qk<<<dim3(4, 16, 16), 256, 0, stream>>>(ht, wbf, bq, bk, qt, ktp);
  k_conv_v <<<dim3(32, 2, 8), 256, 0, stream>>>(ht, wbf + 2 * 65536, bv, vp);
  k_flash  <<<dim3(512), 256, 0, stream>>>(qt, ktp, vp, pop, mlp);
  k_merge  <<<dim3(2048), 256, 0, stream>>>(pop, mlp, aop);
  k_final  <<<dim3(32, 2, 8), 256, 0, stream>>>(aop, wbf + 3 * 65536, bo, x, out);
}